// Round 5
// baseline (209.713 us; speedup 1.0000x reference)
//
#include <hip/hip_runtime.h>
#include <math.h>

#define EPSF 1e-6f
#define LOG2E 1.4426950408889634f

__device__ __forceinline__ float sigmoidf_(float v) { return 1.0f / (1.0f + __expf(-v)); }

// =====================================================================
// Fused single-kernel pipeline: enc -> [grid barrier] -> rho CNN ->
// [grid barrier] -> final interpolation + head.
// Grid: (16,16) = 256 blocks (1 per CU -> co-residency guaranteed), 512 thr.
// Assumes nb=16, npts=2048, M<=320, ntar=256 (fallback otherwise).
// =====================================================================

__device__ __forceinline__ void gbar(unsigned* cnt, unsigned target) {
    __syncthreads();
    __threadfence();   // release: make this block's global writes visible (agent scope)
    if (threadIdx.x == 0) {
        __hip_atomic_fetch_add(cnt, 1u, __ATOMIC_ACQ_REL, __HIP_MEMORY_SCOPE_AGENT);
        int guard = 0;
        while (__hip_atomic_load(cnt, __ATOMIC_ACQUIRE, __HIP_MEMORY_SCOPE_AGENT) < target) {
            __builtin_amdgcn_s_sleep(2);
            if (++guard > (1 << 22)) break;   // safety valve (~0.7s) - never hit when correct
        }
    }
    __syncthreads();
    __threadfence();   // acquire side for all threads (L1 inv)
}

// LDS union: 13120 floats = 52480 B
// P1: spk (float2[3][2048]) = 12288 floats; then red 3000 + tot 120 (reuses spk region)
// P2: WA 5152 | WB 5152 | IN 512 | H1 896 | H2 768 | H3 640 = 13120
// P3: red2 8*16*30 = 3840 | AB 480
#define OFF_WB 5152
#define OFF_IN 10304
#define OFF_H1 10816
#define OFF_H2 11712
#define OFF_H3 12480
#define P1_TOT 3008
#define P3_AB  3840
#define RS 320   // rep col stride / mu row-count pad

__global__ __launch_bounds__(512) void fused_kernel(
    const float* __restrict__ x, const float* __restrict__ y,
    const float* __restrict__ x_out, const float* __restrict__ xg,
    const float* __restrict__ eps, const float* __restrict__ enc_sigma,
    const float* __restrict__ gW, const float* __restrict__ gb,
    const float* __restrict__ w1, const float* __restrict__ b1,
    const float* __restrict__ w2, const float* __restrict__ b2,
    const float* __restrict__ w3, const float* __restrict__ b3,
    const float* __restrict__ linW, const float* __restrict__ linb,
    const float* __restrict__ int_sigma,
    const float* __restrict__ loW, const float* __restrict__ lob,
    unsigned* __restrict__ bar, float* __restrict__ rep,
    float* __restrict__ mu, float* __restrict__ stdv,
    float* __restrict__ out, int nb, int M, int ntar)
{
    __shared__ float smem[13120];
    const int tid = threadIdx.x;
    const int b = blockIdx.y;
    const int bx = blockIdx.x;          // tile index 0..15
    const int c0 = bx * 20;             // 20 grid cols per tile (16*20=320 >= M)

    // ---------------- Phase 1: ConvDeepSet encoder ----------------
    {
        float2* spk = (float2*)smem;    // [c][n], 3*2048
        const float4* x4 = (const float4*)(x + (size_t)b * 6144);
        const float4* y4 = (const float4*)(y + (size_t)b * 6144);
        for (int i = tid; i < 1536; i += 512) {
            float4 xv = x4[i], yv = y4[i];
            float vx[4] = {xv.x, xv.y, xv.z, xv.w};
            float vy[4] = {yv.x, yv.y, yv.z, yv.w};
            #pragma unroll
            for (int j = 0; j < 4; j++) {
                int ee = 4 * i + j, n = ee / 3, c = ee - n * 3;
                spk[c * 2048 + n] = make_float2(vx[j], vy[j]);
            }
        }
        int ic = tid % 20, ng = tid / 20;    // ng 0..25 (25 = stray, guarded)
        int m = c0 + ic;
        bool mv = (m < M) && (ng < 25);
        float e2[3], g[3] = {0, 0, 0};
        #pragma unroll
        for (int c = 0; c < 3; c++) {
            float inv = 1.0f / (__expf(enc_sigma[c]) + EPSF);
            e2[c] = -0.5f * inv * inv * LOG2E;
        }
        if (mv) {
            #pragma unroll
            for (int c = 0; c < 3; c++) g[c] = xg[(size_t)(b * M + m) * 3 + c];
        }
        __syncthreads();
        float h00=0, h01=0, h02=0, h10=0, h11=0, h12=0;
        if (ng < 25) {
            #pragma unroll 2
            for (int n = ng; n < 2048; n += 25) {
                float2 v0 = spk[n];
                float2 v1 = spk[2048 + n];
                float2 v2 = spk[4096 + n];
                float d0 = v0.x - g[0]; float w0 = exp2f(e2[0] * d0 * d0);
                float d1 = v1.x - g[1]; float w1v = exp2f(e2[1] * d1 * d1);
                float d2 = v2.x - g[2]; float w2v = exp2f(e2[2] * d2 * d2);
                h00 += w0; h10 = fmaf(v0.y, w0, h10);
                h01 += w1v; h11 = fmaf(v1.y, w1v, h11);
                h02 += w2v; h12 = fmaf(v2.y, w2v, h12);
            }
        }
        __syncthreads();   // all spk reads done; reuse region for reduction
        float* red = smem; // [25][20][6]
        if (ng < 25) {
            float* rp = red + (ng * 20 + ic) * 6;
            rp[0] = h00; rp[1] = h01; rp[2] = h02;
            rp[3] = h10; rp[4] = h11; rp[5] = h12;
        }
        __syncthreads();
        float* tot = smem + P1_TOT;  // [20][6]
        if (tid < 120) {
            int c = tid / 20, col = tid % 20;
            float s = 0.0f;
            for (int k = 0; k < 25; k++) s += red[(k * 20 + col) * 6 + c];
            tot[col * 6 + c] = s;
        }
        __syncthreads();
        if (tid < 320) {
            int j = tid / 20, ic2 = tid % 20;
            int m2 = c0 + ic2;
            if (m2 < M) {
                const float* tp = tot + ic2 * 6;
                float cat[6];
                #pragma unroll
                for (int c = 0; c < 3; c++) {
                    cat[c] = tp[c];
                    cat[3 + c] = tp[3 + c] / (tp[c] + EPSF);
                }
                float r = gb[j];
                #pragma unroll
                for (int i = 0; i < 6; i++) r = fmaf(cat[i], gW[i * 16 + j], r);
                rep[((size_t)b * 16 + j) * RS + m2] = sigmoidf_(r);
            }
        }
    }

    gbar(bar + 0, 256);

    // ---------------- Phase 2: rho CNN (3 convs) + linear head ----------------
    {
        float* sWA = smem;              // w1 padded (32*81), later w3 (32*161)
        float* sWB = smem + OFF_WB;     // w2 padded (32*161)
        float* sIn = smem + OFF_IN;     // [16][32]
        float* sH1 = smem + OFF_H1;     // [32][28]
        float* sH2 = smem + OFF_H2;     // [32][24]
        float* sH3 = smem + OFF_H3;     // [32][20]
        {
            const float4* w1v = (const float4*)w1;   // 640
            const float4* w2v = (const float4*)w2;   // 1280
            for (int i4 = tid; i4 < 640; i4 += 512) {
                float4 v = w1v[i4];
                float vv[4] = {v.x, v.y, v.z, v.w};
                #pragma unroll
                for (int j = 0; j < 4; j++) {
                    int e = 4 * i4 + j;
                    sWA[(e / 80) * 81 + e % 80] = vv[j];
                }
            }
            for (int i4 = tid; i4 < 1280; i4 += 512) {
                float4 v = w2v[i4];
                float vv[4] = {v.x, v.y, v.z, v.w};
                #pragma unroll
                for (int j = 0; j < 4; j++) {
                    int e = 4 * i4 + j;
                    sWB[(e / 160) * 161 + e % 160] = vv[j];
                }
            }
            {
                int i = tid >> 5, q = tid & 31;
                int col = c0 - 6 + q;
                sIn[i * 32 + q] = (col >= 0 && col < M) ? rep[((size_t)b * 16 + i) * RS + col] : 0.0f;
            }
        }
        __syncthreads();
        int o = tid >> 4, q0 = tid & 15;
        // conv1: 28 cols (global col = c0 - 4 + q), q = q0 (+ q0+16 if q0<12)
        {
            float a0 = b1[o], a1 = a0;
            bool two = (q0 < 12);
            #pragma unroll
            for (int i = 0; i < 16; i++) {
                const float* wp = sWA + o * 81 + i * 5;
                float u0 = wp[0], u1 = wp[1], u2 = wp[2], u3 = wp[3], u4 = wp[4];
                const float* ip = sIn + i * 32;
                a0 = fmaf(ip[q0], u0, a0);     a0 = fmaf(ip[q0+1], u1, a0);
                a0 = fmaf(ip[q0+2], u2, a0);   a0 = fmaf(ip[q0+3], u3, a0);
                a0 = fmaf(ip[q0+4], u4, a0);
                if (two) {
                    a1 = fmaf(ip[q0+16], u0, a1);  a1 = fmaf(ip[q0+17], u1, a1);
                    a1 = fmaf(ip[q0+18], u2, a1);  a1 = fmaf(ip[q0+19], u3, a1);
                    a1 = fmaf(ip[q0+20], u4, a1);
                }
            }
            int g0 = c0 - 4 + q0, g1 = g0 + 16;
            sH1[o * 28 + q0] = (g0 >= 0 && g0 < M) ? fmaxf(a0, 0.0f) : 0.0f;
            if (two) sH1[o * 28 + q0 + 16] = (g1 >= 0 && g1 < M) ? fmaxf(a1, 0.0f) : 0.0f;
        }
        __syncthreads();   // conv1 done reading sWA; sH1 ready
        // w3 early-load (T14): global -> regs; LDS write after conv2
        float4 wreg[3];
        {
            const float4* w3v = (const float4*)w3;   // 1280
            wreg[0] = w3v[tid];
            wreg[1] = w3v[tid + 512];
            if (tid < 256) wreg[2] = w3v[tid + 1024];
        }
        // conv2: 24 cols (global col = c0 - 2 + q), q = q0 (+ q0+16 if q0<8)
        {
            float a0 = b2[o], a1 = a0;
            bool two = (q0 < 8);
            #pragma unroll
            for (int i = 0; i < 32; i++) {
                const float* wp = sWB + o * 161 + i * 5;
                float u0 = wp[0], u1 = wp[1], u2 = wp[2], u3 = wp[3], u4 = wp[4];
                const float* ip = sH1 + i * 28;
                a0 = fmaf(ip[q0], u0, a0);     a0 = fmaf(ip[q0+1], u1, a0);
                a0 = fmaf(ip[q0+2], u2, a0);   a0 = fmaf(ip[q0+3], u3, a0);
                a0 = fmaf(ip[q0+4], u4, a0);
                if (two) {
                    a1 = fmaf(ip[q0+16], u0, a1);  a1 = fmaf(ip[q0+17], u1, a1);
                    a1 = fmaf(ip[q0+18], u2, a1);  a1 = fmaf(ip[q0+19], u3, a1);
                    a1 = fmaf(ip[q0+20], u4, a1);
                }
            }
            int g0 = c0 - 2 + q0, g1 = g0 + 16;
            sH2[o * 24 + q0] = (g0 >= 0 && g0 < M) ? fmaxf(a0, 0.0f) : 0.0f;
            if (two) sH2[o * 24 + q0 + 16] = (g1 >= 0 && g1 < M) ? fmaxf(a1, 0.0f) : 0.0f;
        }
        // write w3 into sWA (padded stride 161)
        {
            #pragma unroll
            for (int h = 0; h < 3; h++) {
                if (h == 2 && tid >= 256) break;
                float vv[4] = {wreg[h].x, wreg[h].y, wreg[h].z, wreg[h].w};
                #pragma unroll
                for (int j = 0; j < 4; j++) {
                    int e = 4 * (tid + 512 * h) + j;
                    sWA[(e / 160) * 161 + e % 160] = vv[j];
                }
            }
        }
        __syncthreads();   // sH2 + w3 ready
        // conv3: 20 cols (global col = c0 + q), q = q0 (+ q0+16 if q0<4), no relu
        {
            float a0 = b3[o], a1 = a0;
            bool two = (q0 < 4);
            #pragma unroll
            for (int i = 0; i < 32; i++) {
                const float* wp = sWA + o * 161 + i * 5;
                float u0 = wp[0], u1 = wp[1], u2 = wp[2], u3 = wp[3], u4 = wp[4];
                const float* ip = sH2 + i * 24;
                a0 = fmaf(ip[q0], u0, a0);     a0 = fmaf(ip[q0+1], u1, a0);
                a0 = fmaf(ip[q0+2], u2, a0);   a0 = fmaf(ip[q0+3], u3, a0);
                a0 = fmaf(ip[q0+4], u4, a0);
                if (two) {
                    a1 = fmaf(ip[q0+16], u0, a1);  a1 = fmaf(ip[q0+17], u1, a1);
                    a1 = fmaf(ip[q0+18], u2, a1);  a1 = fmaf(ip[q0+19], u3, a1);
                    a1 = fmaf(ip[q0+20], u4, a1);
                }
            }
            sH3[o * 20 + q0] = a0;
            if (two) sH3[o * 20 + q0 + 16] = a1;
        }
        __syncthreads();
        // head: 20 cols x 30 outs = 600
        for (int idx = tid; idx < 600; idx += 512) {
            int q = idx / 30, j = idx % 30;
            int m = c0 + q;
            if (m < M) {
                float v = linb[j];
                #pragma unroll
                for (int oo = 0; oo < 32; oo++) v = fmaf(sH3[oo * 20 + q], linW[oo * 30 + j], v);
                if (j < 15) mu[((size_t)b * RS + m) * 16 + j] = v;
                else        stdv[((size_t)b * RS + m) * 16 + (j - 15)] = 0.1f + 0.9f * sigmoidf_(v);
            }
        }
    }

    gbar(bar + 1, 256);

    // ---------------- Phase 3: interpolation + output head ----------------
    {
        float* red2 = smem;            // [8][16][30]
        float* AB = smem + P3_AB;      // [16][30]
        int ti = tid & 15, mg = tid >> 4;   // 16 targets x 32 m-groups
        int t = bx * 16 + ti;
        bool tv = (t < ntar);
        float xt[3] = {0, 0, 0};
        if (tv) {
            #pragma unroll
            for (int c = 0; c < 3; c++) xt[c] = x_out[((size_t)b * ntar + t) * 3 + c];
        }
        float k2[15];
        #pragma unroll
        for (int k = 0; k < 15; k++) {
            float inv = 1.0f / (__expf(int_sigma[k]) + EPSF);
            k2[k] = -0.5f * inv * inv * LOG2E;
        }
        float A[15], B[15];
        #pragma unroll
        for (int k = 0; k < 15; k++) { A[k] = 0.0f; B[k] = 0.0f; }
        for (int m = mg; m < M; m += 32) {
            const float* gp = xg + (size_t)(b * M + m) * 3;
            float gv[3] = {gp[0], gp[1], gp[2]};
            const float4* mup = (const float4*)(mu + ((size_t)b * RS + m) * 16);
            const float4* sdp = (const float4*)(stdv + ((size_t)b * RS + m) * 16);
            float4 a0 = mup[0], a1 = mup[1], a2 = mup[2], a3 = mup[3];
            float4 s0 = sdp[0], s1 = sdp[1], s2 = sdp[2], s3 = sdp[3];
            float mv[16] = {a0.x,a0.y,a0.z,a0.w, a1.x,a1.y,a1.z,a1.w,
                            a2.x,a2.y,a2.z,a2.w, a3.x,a3.y,a3.z,a3.w};
            float sv[16] = {s0.x,s0.y,s0.z,s0.w, s1.x,s1.y,s1.z,s1.w,
                            s2.x,s2.y,s2.z,s2.w, s3.x,s3.y,s3.z,s3.w};
            #pragma unroll
            for (int k = 0; k < 15; k++) {
                int c = k % 3;
                float d = gv[c] - xt[c];
                float w = exp2f(k2[k] * d * d);
                A[k] = fmaf(mv[k], w, A[k]);
                B[k] = fmaf(sv[k], w, B[k]);
            }
        }
        // in-wave reduce over mg bits 0,1 (lane bits 4,5)
        #pragma unroll
        for (int mask = 16; mask <= 32; mask <<= 1) {
            #pragma unroll
            for (int k = 0; k < 15; k++) {
                A[k] += __shfl_xor(A[k], mask, 64);
                B[k] += __shfl_xor(B[k], mask, 64);
            }
        }
        int lane = tid & 63, wv = tid >> 6;
        if (lane < 16) {
            float* rp = red2 + (wv * 16 + lane) * 30;
            #pragma unroll
            for (int k = 0; k < 15; k++) { rp[k] = A[k]; rp[15 + k] = B[k]; }
        }
        __syncthreads();
        if (tid < 480) {
            int t2 = tid / 30, v = tid % 30;
            float s = 0.0f;
            #pragma unroll
            for (int w = 0; w < 8; w++) s += red2[(w * 16 + t2) * 30 + v];
            AB[t2 * 30 + v] = s;
        }
        __syncthreads();
        if (tid < 384) {
            int t2 = tid / 24, rem = tid % 24;
            int s = rem / 6, j = rem % 6;
            int tg = bx * 16 + t2;
            if (tg < ntar) {
                float val = lob[j];
                const float* ep = eps + ((size_t)s * nb + b) * 15;
                const float* ab = AB + t2 * 30;
                #pragma unroll
                for (int k = 0; k < 15; k++) {
                    float h = fmaf(ep[k], ab[15 + k], ab[k]);
                    val = fmaf(h, loW[k * 6 + j], val);
                }
                if (j >= 3) val = fmaxf(val, 0.0f) + log1pf(__expf(-fabsf(val)));  // softplus
                out[(((size_t)s * nb + b) * ntar + tg) * 6 + j] = val;
            }
        }
    }
}

// =====================================================================
// Fallback 3-kernel path (generic shapes) — same as previous passing version
// =====================================================================

__global__ __launch_bounds__(1024) void enc_kernel_g(
    const float* __restrict__ x, const float* __restrict__ y,
    const float* __restrict__ xg, const float* __restrict__ enc_sigma,
    const float* __restrict__ gW, const float* __restrict__ gb,
    float* __restrict__ rep_s, int nb, int npts, int M)
{
    __shared__ float sx[6144];
    __shared__ float sy[6144];
    __shared__ float red[16][8][6];
    __shared__ float tot[8][6];
    int b = blockIdx.y;
    int mt = blockIdx.x * 8;
    int tid = threadIdx.x;
    int n3 = npts * 3;
    for (int i = tid; i < n3; i += 1024) {
        sx[i] = x[(size_t)b * n3 + i];
        sy[i] = y[(size_t)b * n3 + i];
    }
    int mi = tid & 7, ng = tid >> 3;
    int m = mt + mi;
    bool mv = (m < M);
    float e1[3], g[3];
    for (int c = 0; c < 3; c++) {
        float inv = 1.0f / (__expf(enc_sigma[c]) + EPSF);
        e1[c] = -0.5f * inv * inv;
    }
    for (int c = 0; c < 3; c++) g[c] = mv ? xg[(size_t)(b * M + m) * 3 + c] : 0.0f;
    __syncthreads();
    float h0[3] = {0,0,0}, h1[3] = {0,0,0};
    for (int n = ng; n < npts; n += 128) {
        for (int c = 0; c < 3; c++) {
            float d = sx[n * 3 + c] - g[c];
            float w = __expf(e1[c] * d * d);
            h0[c] += w;
            h1[c] = fmaf(sy[n * 3 + c], w, h1[c]);
        }
    }
    for (int mask = 8; mask <= 32; mask <<= 1) {
        for (int c = 0; c < 3; c++) {
            h0[c] += __shfl_xor(h0[c], mask, 64);
            h1[c] += __shfl_xor(h1[c], mask, 64);
        }
    }
    int lane = tid & 63, wv = tid >> 6;
    if (lane < 8) {
        for (int c = 0; c < 3; c++) { red[wv][lane][c] = h0[c]; red[wv][lane][3 + c] = h1[c]; }
    }
    __syncthreads();
    if (tid < 48) {
        int mi2 = tid & 7, c2 = tid >> 3;
        float s = 0.0f;
        for (int k = 0; k < 16; k++) s += red[k][mi2][c2];
        tot[mi2][c2] = s;
    }
    __syncthreads();
    if (tid < 128) {
        int mi2 = tid & 7, j = tid >> 3;
        int m2 = mt + mi2;
        if (m2 < M) {
            float cat[6];
            for (int c = 0; c < 3; c++) {
                cat[c] = tot[mi2][c];
                cat[3 + c] = tot[mi2][3 + c] / (tot[mi2][c] + EPSF);
            }
            float r = gb[j];
            for (int i = 0; i < 6; i++) r = fmaf(cat[i], gW[i * 16 + j], r);
            rep_s[((size_t)b * 16 + j) * M + m2] = sigmoidf_(r);
        }
    }
}

__global__ __launch_bounds__(256) void rho_kernel_g(
    const float* __restrict__ rep_s,
    const float* __restrict__ w1, const float* __restrict__ b1,
    const float* __restrict__ w2, const float* __restrict__ b2,
    const float* __restrict__ w3, const float* __restrict__ b3,
    const float* __restrict__ linW, const float* __restrict__ linb,
    float* __restrict__ mu, float* __restrict__ stdv,
    int nb, int M)
{
    __shared__ float sWA[5152];
    __shared__ float sWB[5152];
    __shared__ float sIn[16][20];
    __shared__ float sH1[32][16];
    __shared__ float sH2[32][12];
    __shared__ float sH3[32][8];
    int b = blockIdx.y;
    int t0 = blockIdx.x * 8;
    int tid = threadIdx.x;
    {
        const float4* w1v = (const float4*)w1;
        const float4* w2v = (const float4*)w2;
        for (int i4 = tid; i4 < 640; i4 += 256) {
            float4 v = w1v[i4];
            float vv[4] = {v.x, v.y, v.z, v.w};
            for (int j = 0; j < 4; j++) {
                int e = 4 * i4 + j;
                sWA[(e / 80) * 81 + e % 80] = vv[j];
            }
        }
        for (int i4 = tid; i4 < 1280; i4 += 256) {
            float4 v = w2v[i4];
            float vv[4] = {v.x, v.y, v.z, v.w};
            for (int j = 0; j < 4; j++) {
                int e = 4 * i4 + j;
                sWB[(e / 160) * 161 + e % 160] = vv[j];
            }
        }
        for (int idx = tid; idx < 16 * 20; idx += 256) {
            int i = idx / 20, q = idx % 20;
            int mg = t0 - 6 + q;
            sIn[i][q] = (mg >= 0 && mg < M) ? rep_s[((size_t)b * 16 + i) * M + mg] : 0.0f;
        }
    }
    __syncthreads();
    int o = tid >> 3, q0 = tid & 7;
    {
        float a0 = b1[o], a1 = a0;
        for (int i = 0; i < 16; i++) {
            const float* wp = sWA + o * 81 + i * 5;
            float u0 = wp[0], u1 = wp[1], u2 = wp[2], u3 = wp[3], u4 = wp[4];
            const float* ip = &sIn[i][0];
            a0 = fmaf(ip[q0], u0, a0);      a0 = fmaf(ip[q0+1], u1, a0);
            a0 = fmaf(ip[q0+2], u2, a0);    a0 = fmaf(ip[q0+3], u3, a0);
            a0 = fmaf(ip[q0+4], u4, a0);
            a1 = fmaf(ip[q0+8], u0, a1);    a1 = fmaf(ip[q0+9], u1, a1);
            a1 = fmaf(ip[q0+10], u2, a1);   a1 = fmaf(ip[q0+11], u3, a1);
            a1 = fmaf(ip[q0+12], u4, a1);
        }
        int g0 = t0 - 4 + q0, g1 = g0 + 8;
        sH1[o][q0]     = (g0 >= 0 && g0 < M) ? fmaxf(a0, 0.0f) : 0.0f;
        sH1[o][q0 + 8] = (g1 >= 0 && g1 < M) ? fmaxf(a1, 0.0f) : 0.0f;
    }
    __syncthreads();
    float4 wreg[5];
    {
        const float4* w3v = (const float4*)w3;
        for (int h = 0; h < 5; h++) wreg[h] = w3v[tid + 256 * h];
    }
    {
        float a0 = b2[o], a1 = a0;
        bool second = (q0 < 4);
        for (int i = 0; i < 32; i++) {
            const float* wp = sWB + o * 161 + i * 5;
            float u0 = wp[0], u1 = wp[1], u2 = wp[2], u3 = wp[3], u4 = wp[4];
            const float* ip = &sH1[i][0];
            a0 = fmaf(ip[q0], u0, a0);      a0 = fmaf(ip[q0+1], u1, a0);
            a0 = fmaf(ip[q0+2], u2, a0);    a0 = fmaf(ip[q0+3], u3, a0);
            a0 = fmaf(ip[q0+4], u4, a0);
            if (second) {
                a1 = fmaf(ip[q0+8], u0, a1);    a1 = fmaf(ip[q0+9], u1, a1);
                a1 = fmaf(ip[q0+10], u2, a1);   a1 = fmaf(ip[q0+11], u3, a1);
                a1 = fmaf(ip[q0+12], u4, a1);
            }
        }
        int g0 = t0 - 2 + q0, g1 = g0 + 8;
        sH2[o][q0] = (g0 >= 0 && g0 < M) ? fmaxf(a0, 0.0f) : 0.0f;
        if (second) sH2[o][q0 + 8] = (g1 >= 0 && g1 < M) ? fmaxf(a1, 0.0f) : 0.0f;
    }
    for (int h = 0; h < 5; h++) {
        float vv[4] = {wreg[h].x, wreg[h].y, wreg[h].z, wreg[h].w};
        for (int j = 0; j < 4; j++) {
            int e = 4 * (tid + 256 * h) + j;
            sWA[(e / 160) * 161 + e % 160] = vv[j];
        }
    }
    __syncthreads();
    {
        float a0 = b3[o];
        for (int i = 0; i < 32; i++) {
            const float* wp = sWA + o * 161 + i * 5;
            float u0 = wp[0], u1 = wp[1], u2 = wp[2], u3 = wp[3], u4 = wp[4];
            const float* ip = &sH2[i][0];
            a0 = fmaf(ip[q0], u0, a0);      a0 = fmaf(ip[q0+1], u1, a0);
            a0 = fmaf(ip[q0+2], u2, a0);    a0 = fmaf(ip[q0+3], u3, a0);
            a0 = fmaf(ip[q0+4], u4, a0);
        }
        sH3[o][q0] = a0;
    }
    __syncthreads();
    if (tid < 240) {
        int q = tid / 30, j = tid % 30;
        int m = t0 + q;
        if (m < M) {
            float v = linb[j];
            for (int oo = 0; oo < 32; oo++) v = fmaf(sH3[oo][q], linW[oo * 30 + j], v);
            if (j < 15) mu[((size_t)b * M + m) * 16 + j] = v;
            else        stdv[((size_t)b * M + m) * 16 + (j - 15)] = 0.1f + 0.9f * sigmoidf_(v);
        }
    }
}

__global__ void final_kernel_g(const float* __restrict__ x_out, const float* __restrict__ xg,
                               const float* __restrict__ int_sigma, const float* __restrict__ eps,
                               const float* __restrict__ mu, const float* __restrict__ stdv,
                               const float* __restrict__ loW, const float* __restrict__ lob,
                               float* __restrict__ out, int nb, int ntar, int M)
{
    __shared__ float red2[4][8][30];
    __shared__ float AB[8][30];
    int b = blockIdx.y;
    int tt = blockIdx.x * 8;
    int tid = threadIdx.x;
    int ti = tid & 7, mg = tid >> 3;
    int t = tt + ti;
    bool tv = (t < ntar);
    float xt[3];
    for (int c = 0; c < 3; c++) xt[c] = tv ? x_out[((size_t)b * ntar + t) * 3 + c] : 0.0f;
    float k2[15];
    for (int k = 0; k < 15; k++) {
        float inv = 1.0f / (__expf(int_sigma[k]) + EPSF);
        k2[k] = -0.5f * inv * inv;
    }
    float A[15], B[15];
    for (int k = 0; k < 15; k++) { A[k] = 0.0f; B[k] = 0.0f; }
    for (int m = mg; m < M; m += 32) {
        const float* gp = xg + (size_t)(b * M + m) * 3;
        float gv[3] = {gp[0], gp[1], gp[2]};
        const float* mup = mu + ((size_t)b * M + m) * 16;
        const float* sdp = stdv + ((size_t)b * M + m) * 16;
        for (int k = 0; k < 15; k++) {
            int c = k % 3;
            float d = gv[c] - xt[c];
            float w = __expf(k2[k] * d * d);
            A[k] = fmaf(mup[k], w, A[k]);
            B[k] = fmaf(sdp[k], w, B[k]);
        }
    }
    for (int mask = 8; mask <= 32; mask <<= 1) {
        for (int k = 0; k < 15; k++) {
            A[k] += __shfl_xor(A[k], mask, 64);
            B[k] += __shfl_xor(B[k], mask, 64);
        }
    }
    int lane = tid & 63, wv = tid >> 6;
    if (lane < 8) {
        for (int k = 0; k < 15; k++) { red2[wv][lane][k] = A[k]; red2[wv][lane][15 + k] = B[k]; }
    }
    __syncthreads();
    for (int idx = tid; idx < 240; idx += 256) {
        int t2 = idx / 30, v = idx % 30;
        AB[t2][v] = red2[0][t2][v] + red2[1][t2][v] + red2[2][t2][v] + red2[3][t2][v];
    }
    __syncthreads();
    if (tid < 192) {
        int t2 = tid / 24;
        int rem = tid % 24;
        int s = rem / 6, j = rem % 6;
        int tg = tt + t2;
        if (tg < ntar) {
            float val = lob[j];
            const float* ep = eps + ((size_t)s * nb + b) * 15;
            for (int k = 0; k < 15; k++) {
                float h = fmaf(ep[k], AB[t2][15 + k], AB[t2][k]);
                val = fmaf(h, loW[k * 6 + j], val);
            }
            if (j >= 3) val = fmaxf(val, 0.0f) + log1pf(__expf(-fabsf(val)));
            out[(((size_t)s * nb + b) * ntar + tg) * 6 + j] = val;
        }
    }
}

extern "C" void kernel_launch(void* const* d_in, const int* in_sizes, int n_in,
                              void* d_out, int out_size, void* d_ws, size_t ws_size,
                              hipStream_t stream)
{
    const float* x         = (const float*)d_in[0];
    const float* y         = (const float*)d_in[1];
    const float* x_out     = (const float*)d_in[2];
    const float* x_grid    = (const float*)d_in[3];
    const float* eps_noise = (const float*)d_in[4];
    const float* enc_sigma = (const float*)d_in[5];
    const float* gW        = (const float*)d_in[6];
    const float* gb        = (const float*)d_in[7];
    const float* w1        = (const float*)d_in[8];
    const float* b1        = (const float*)d_in[9];
    const float* w2        = (const float*)d_in[10];
    const float* b2        = (const float*)d_in[11];
    const float* w3        = (const float*)d_in[12];
    const float* b3        = (const float*)d_in[13];
    const float* linW      = (const float*)d_in[14];
    const float* linb      = (const float*)d_in[15];
    const float* int_sigma = (const float*)d_in[16];
    const float* loW       = (const float*)d_in[17];
    const float* lob       = (const float*)d_in[18];
    float* out = (float*)d_out;

    const int NS = 4, C = 3, NBASIS = 5;
    int nb   = in_sizes[4] / (NS * C * NBASIS);       // eps_noise: (NS, nb, 15)
    int npts = in_sizes[0] / (nb * C);
    int ntar = in_sizes[2] / (nb * C);
    int M    = in_sizes[3] / (nb * C);

    bool fast = (nb == 16 && npts == 2048 && ntar == 256 && M >= 21 && M <= 320);
    if (fast) {
        unsigned* bar = (unsigned*)d_ws;
        float* rep  = (float*)((char*)d_ws + 256);     // (16, 16, 320)
        float* mu   = rep + 16 * 16 * 320;             // (16, 320, 16)
        float* stdv = mu + 16 * 320 * 16;              // (16, 320, 16)
        hipMemsetAsync(d_ws, 0, 64, stream);
        fused_kernel<<<dim3(16, 16), 512, 0, stream>>>(
            x, y, x_out, x_grid, eps_noise, enc_sigma, gW, gb,
            w1, b1, w2, b2, w3, b3, linW, linb, int_sigma, loW, lob,
            bar, rep, mu, stdv, out, nb, M, ntar);
    } else {
        float* rep_s = (float*)d_ws;                       // (nb, 16, M)
        float* mu    = rep_s + (size_t)nb * 16 * M;        // (nb, M, 16)
        float* stdv  = mu + (size_t)nb * M * 16;           // (nb, M, 16)
        enc_kernel_g<<<dim3((M + 7) / 8, nb), 1024, 0, stream>>>(
            x, y, x_grid, enc_sigma, gW, gb, rep_s, nb, npts, M);
        rho_kernel_g<<<dim3((M + 7) / 8, nb), 256, 0, stream>>>(
            rep_s, w1, b1, w2, b2, w3, b3, linW, linb, mu, stdv, nb, M);
        final_kernel_g<<<dim3((ntar + 7) / 8, nb), 256, 0, stream>>>(
            x_out, x_grid, int_sigma, eps_noise, mu, stdv, loW, lob, out, nb, ntar, M);
    }
}

// Round 6
// 81.804 us; speedup vs baseline: 2.5636x; 2.5636x over previous
//
#include <hip/hip_runtime.h>
#include <math.h>

#define EPSF 1e-6f
#define LOG2E 1.4426950408889634f

__device__ __forceinline__ float sigmoidf_(float v) { return 1.0f / (1.0f + __expf(-v)); }

// =====================================================================
// K1: fused enc + rho per 20-col tile (halo recompute, LDS handoff).
// grid (16, nb), 512 threads. Assumes npts=2048, M<=320.
// LDS layout (floats):
//   [0,5152)      sWA  (w1 padded 81, later w3 padded 161)   | phase A: spk
//   [5152,10304)  sWB  (w2 padded 161)                        | phase A: spk
//   [10304,12288) spk tail
//   [12288,13824) red  [8 waves][32 ic][6]
//   [13824,14016) tot  [32 ic][6]
//   [14016,14528) sIn  [16][32]
//   [14528,15424) sH1  [32][28]
//   [15424,16192) sH2  [32][24]
//   [16192,16832) sH3  [32][20]
// total 16832 floats = 67328 B
// =====================================================================
__global__ __launch_bounds__(512) void encrho_kernel(
    const float* __restrict__ x, const float* __restrict__ y,
    const float* __restrict__ xg, const float* __restrict__ enc_sigma,
    const float* __restrict__ gW, const float* __restrict__ gb,
    const float* __restrict__ w1, const float* __restrict__ b1,
    const float* __restrict__ w2, const float* __restrict__ b2,
    const float* __restrict__ w3, const float* __restrict__ b3,
    const float* __restrict__ linW, const float* __restrict__ linb,
    float* __restrict__ mu, float* __restrict__ stdv,
    int nb, int M)
{
    __shared__ float smem[16832];
    float* sWA = smem;
    float* sWB = smem + 5152;
    float2* spk = (float2*)smem;        // [c][2048]
    float* red = smem + 12288;
    float* tot = smem + 13824;
    float* sIn = smem + 14016;
    float* sH1 = smem + 14528;
    float* sH2 = smem + 15424;
    float* sH3 = smem + 16192;

    const int tid = threadIdx.x;
    const int b = blockIdx.y;
    const int c0 = blockIdx.x * 20;

    // ---------------- Phase A: encoder over 32 cols (c0-6 .. c0+25) ----------------
    {
        const float4* x4 = (const float4*)(x + (size_t)b * 6144);
        const float4* y4 = (const float4*)(y + (size_t)b * 6144);
        #pragma unroll
        for (int r = 0; r < 3; r++) {
            int i = tid + 512 * r;
            float4 xv = x4[i], yv = y4[i];
            float vx[4] = {xv.x, xv.y, xv.z, xv.w};
            float vy[4] = {yv.x, yv.y, yv.z, yv.w};
            #pragma unroll
            for (int j = 0; j < 4; j++) {
                int ee = 4 * i + j, n = ee / 3, c = ee - n * 3;
                spk[c * 2048 + n] = make_float2(vx[j], vy[j]);
            }
        }
        int ic = tid & 31, ng = tid >> 5;    // 32 cols x 16 n-groups
        int mg = c0 - 6 + ic;
        bool cv = (mg >= 0 && mg < M);
        float e2[3], g[3] = {0, 0, 0};
        #pragma unroll
        for (int c = 0; c < 3; c++) {
            float inv = 1.0f / (__expf(enc_sigma[c]) + EPSF);
            e2[c] = -0.5f * inv * inv * LOG2E;
        }
        if (cv) {
            #pragma unroll
            for (int c = 0; c < 3; c++) g[c] = xg[(size_t)(b * M + mg) * 3 + c];
        }
        __syncthreads();
        float h[6] = {0, 0, 0, 0, 0, 0};
        #pragma unroll 4
        for (int n = ng; n < 2048; n += 16) {
            float2 v0 = spk[n];
            float2 v1 = spk[2048 + n];
            float2 v2 = spk[4096 + n];
            float d0 = v0.x - g[0]; float w0 = exp2f(e2[0] * d0 * d0);
            float d1 = v1.x - g[1]; float w1v = exp2f(e2[1] * d1 * d1);
            float d2 = v2.x - g[2]; float w2v = exp2f(e2[2] * d2 * d2);
            h[0] += w0; h[3] = fmaf(v0.y, w0, h[3]);
            h[1] += w1v; h[4] = fmaf(v1.y, w1v, h[4]);
            h[2] += w2v; h[5] = fmaf(v2.y, w2v, h[5]);
        }
        __syncthreads();   // spk dead; WA/WB region reusable
        // combine ng pairs within wave (lane ^ 32), then LDS-reduce 8 waves
        #pragma unroll
        for (int c = 0; c < 6; c++) h[c] += __shfl_xor(h[c], 32, 64);
        int lane = tid & 63, wv = tid >> 6;
        if (lane < 32) {
            float* rp = red + wv * 192 + lane * 6;
            #pragma unroll
            for (int c = 0; c < 6; c++) rp[c] = h[c];
        }
        // stage w1 (padded 81) and w2 (padded 161) concurrently
        {
            const float4* w1v4 = (const float4*)w1;   // 640
            const float4* w2v4 = (const float4*)w2;   // 1280
            {
                int i4 = tid;
                if (i4 < 640) {
                    float4 v = w1v4[i4];
                    float vv[4] = {v.x, v.y, v.z, v.w};
                    #pragma unroll
                    for (int j = 0; j < 4; j++) {
                        int e = 4 * i4 + j;
                        sWA[(e / 80) * 81 + e % 80] = vv[j];
                    }
                }
                if (i4 + 512 < 640) {  // unreachable for 512 threads; kept for clarity
                }
            }
            if (tid < 128) {
                int i4 = tid + 512;
                float4 v = w1v4[i4];
                float vv[4] = {v.x, v.y, v.z, v.w};
                #pragma unroll
                for (int j = 0; j < 4; j++) {
                    int e = 4 * i4 + j;
                    sWA[(e / 80) * 81 + e % 80] = vv[j];
                }
            }
            for (int i4 = tid; i4 < 1280; i4 += 512) {
                float4 v = w2v4[i4];
                float vv[4] = {v.x, v.y, v.z, v.w};
                #pragma unroll
                for (int j = 0; j < 4; j++) {
                    int e = 4 * i4 + j;
                    sWB[(e / 160) * 161 + e % 160] = vv[j];
                }
            }
        }
        __syncthreads();
        if (tid < 192) {
            int ic2 = tid & 31, c = tid >> 5;
            float s = 0.0f;
            #pragma unroll
            for (int w = 0; w < 8; w++) s += red[w * 192 + ic2 * 6 + c];
            tot[ic2 * 6 + c] = s;
        }
        __syncthreads();
        {
            int j = tid >> 5, ic2 = tid & 31;
            int mg2 = c0 - 6 + ic2;
            float v = 0.0f;
            if (mg2 >= 0 && mg2 < M) {
                const float* tp = tot + ic2 * 6;
                float cat[6];
                #pragma unroll
                for (int c = 0; c < 3; c++) {
                    cat[c] = tp[c];
                    cat[3 + c] = tp[3 + c] / (tp[c] + EPSF);
                }
                float r = gb[j];
                #pragma unroll
                for (int i = 0; i < 6; i++) r = fmaf(cat[i], gW[i * 16 + j], r);
                v = sigmoidf_(r);
            }
            sIn[j * 32 + ic2] = v;
        }
    }
    __syncthreads();

    // ---------------- Phase B: rho CNN + head (as proven R4/R5 structure) ----------------
    {
        int o = tid >> 4, q0 = tid & 15;
        // conv1: 28 cols (global col = c0 - 4 + q), q = q0 (+ q0+16 if q0<12)
        {
            float a0 = b1[o], a1 = a0;
            bool two = (q0 < 12);
            #pragma unroll
            for (int i = 0; i < 16; i++) {
                const float* wp = sWA + o * 81 + i * 5;
                float u0 = wp[0], u1 = wp[1], u2 = wp[2], u3 = wp[3], u4 = wp[4];
                const float* ip = sIn + i * 32;
                a0 = fmaf(ip[q0], u0, a0);     a0 = fmaf(ip[q0+1], u1, a0);
                a0 = fmaf(ip[q0+2], u2, a0);   a0 = fmaf(ip[q0+3], u3, a0);
                a0 = fmaf(ip[q0+4], u4, a0);
                if (two) {
                    a1 = fmaf(ip[q0+16], u0, a1);  a1 = fmaf(ip[q0+17], u1, a1);
                    a1 = fmaf(ip[q0+18], u2, a1);  a1 = fmaf(ip[q0+19], u3, a1);
                    a1 = fmaf(ip[q0+20], u4, a1);
                }
            }
            int g0 = c0 - 4 + q0, g1 = g0 + 16;
            sH1[o * 28 + q0] = (g0 >= 0 && g0 < M) ? fmaxf(a0, 0.0f) : 0.0f;
            if (two) sH1[o * 28 + q0 + 16] = (g1 >= 0 && g1 < M) ? fmaxf(a1, 0.0f) : 0.0f;
        }
        __syncthreads();   // conv1 done reading sWA; sH1 ready
        // w3 early-load: global -> regs; LDS write after conv2
        float4 wreg[3];
        {
            const float4* w3v = (const float4*)w3;   // 1280
            wreg[0] = w3v[tid];
            wreg[1] = w3v[tid + 512];
            if (tid < 256) wreg[2] = w3v[tid + 1024];
        }
        // conv2: 24 cols (global col = c0 - 2 + q), q = q0 (+ q0+16 if q0<8)
        {
            float a0 = b2[o], a1 = a0;
            bool two = (q0 < 8);
            #pragma unroll
            for (int i = 0; i < 32; i++) {
                const float* wp = sWB + o * 161 + i * 5;
                float u0 = wp[0], u1 = wp[1], u2 = wp[2], u3 = wp[3], u4 = wp[4];
                const float* ip = sH1 + i * 28;
                a0 = fmaf(ip[q0], u0, a0);     a0 = fmaf(ip[q0+1], u1, a0);
                a0 = fmaf(ip[q0+2], u2, a0);   a0 = fmaf(ip[q0+3], u3, a0);
                a0 = fmaf(ip[q0+4], u4, a0);
                if (two) {
                    a1 = fmaf(ip[q0+16], u0, a1);  a1 = fmaf(ip[q0+17], u1, a1);
                    a1 = fmaf(ip[q0+18], u2, a1);  a1 = fmaf(ip[q0+19], u3, a1);
                    a1 = fmaf(ip[q0+20], u4, a1);
                }
            }
            int g0 = c0 - 2 + q0, g1 = g0 + 16;
            sH2[o * 24 + q0] = (g0 >= 0 && g0 < M) ? fmaxf(a0, 0.0f) : 0.0f;
            if (two) sH2[o * 24 + q0 + 16] = (g1 >= 0 && g1 < M) ? fmaxf(a1, 0.0f) : 0.0f;
        }
        // write w3 into sWA (padded 161)
        {
            #pragma unroll
            for (int hh = 0; hh < 3; hh++) {
                if (hh == 2 && tid >= 256) break;
                float vv[4] = {wreg[hh].x, wreg[hh].y, wreg[hh].z, wreg[hh].w};
                #pragma unroll
                for (int j = 0; j < 4; j++) {
                    int e = 4 * (tid + 512 * hh) + j;
                    sWA[(e / 160) * 161 + e % 160] = vv[j];
                }
            }
        }
        __syncthreads();   // sH2 + w3 ready
        // conv3: 20 cols (global col = c0 + q), q = q0 (+ q0+16 if q0<4), no relu
        {
            float a0 = b3[o], a1 = a0;
            bool two = (q0 < 4);
            #pragma unroll
            for (int i = 0; i < 32; i++) {
                const float* wp = sWA + o * 161 + i * 5;
                float u0 = wp[0], u1 = wp[1], u2 = wp[2], u3 = wp[3], u4 = wp[4];
                const float* ip = sH2 + i * 24;
                a0 = fmaf(ip[q0], u0, a0);     a0 = fmaf(ip[q0+1], u1, a0);
                a0 = fmaf(ip[q0+2], u2, a0);   a0 = fmaf(ip[q0+3], u3, a0);
                a0 = fmaf(ip[q0+4], u4, a0);
                if (two) {
                    a1 = fmaf(ip[q0+16], u0, a1);  a1 = fmaf(ip[q0+17], u1, a1);
                    a1 = fmaf(ip[q0+18], u2, a1);  a1 = fmaf(ip[q0+19], u3, a1);
                    a1 = fmaf(ip[q0+20], u4, a1);
                }
            }
            sH3[o * 20 + q0] = a0;
            if (two) sH3[o * 20 + q0 + 16] = a1;
        }
        __syncthreads();
        // head: 20 cols x 30 outs = 600
        for (int idx = tid; idx < 600; idx += 512) {
            int q = idx / 30, j = idx % 30;
            int m = c0 + q;
            if (m < M) {
                float v = linb[j];
                #pragma unroll
                for (int oo = 0; oo < 32; oo++) v = fmaf(sH3[oo * 20 + q], linW[oo * 30 + j], v);
                if (j < 15) mu[((size_t)b * M + m) * 16 + j] = v;
                else        stdv[((size_t)b * M + m) * 16 + (j - 15)] = 0.1f + 0.9f * sigmoidf_(v);
            }
        }
    }
}

// ---------------- K2: FinalLayer interpolation + output head ----------------
// grid: (ceil(ntar/8), nb), block 256 (32 m-groups x 8 t); mu/stdv row stride 16
__global__ void final_kernel(const float* __restrict__ x_out, const float* __restrict__ xg,
                             const float* __restrict__ int_sigma, const float* __restrict__ eps,
                             const float* __restrict__ mu, const float* __restrict__ stdv,
                             const float* __restrict__ loW, const float* __restrict__ lob,
                             float* __restrict__ out, int nb, int ntar, int M)
{
    __shared__ float red2[4][8][30];
    __shared__ float AB[8][30];
    int b = blockIdx.y;
    int tt = blockIdx.x * 8;
    int tid = threadIdx.x;
    int ti = tid & 7, mg = tid >> 3;
    int t = tt + ti;
    bool tv = (t < ntar);
    float xt[3];
    for (int c = 0; c < 3; c++) xt[c] = tv ? x_out[((size_t)b * ntar + t) * 3 + c] : 0.0f;
    float k2[15];
    #pragma unroll
    for (int k = 0; k < 15; k++) {
        float inv = 1.0f / (__expf(int_sigma[k]) + EPSF);
        k2[k] = -0.5f * inv * inv * LOG2E;
    }
    float A[15], B[15];
    #pragma unroll
    for (int k = 0; k < 15; k++) { A[k] = 0.0f; B[k] = 0.0f; }
    for (int m = mg; m < M; m += 32) {
        const float* gp = xg + (size_t)(b * M + m) * 3;
        float gv[3] = {gp[0], gp[1], gp[2]};
        const float4* mup = (const float4*)(mu + ((size_t)b * M + m) * 16);
        const float4* sdp = (const float4*)(stdv + ((size_t)b * M + m) * 16);
        float4 a0 = mup[0], a1 = mup[1], a2 = mup[2], a3 = mup[3];
        float4 s0 = sdp[0], s1 = sdp[1], s2 = sdp[2], s3 = sdp[3];
        float mv[16] = {a0.x,a0.y,a0.z,a0.w, a1.x,a1.y,a1.z,a1.w,
                        a2.x,a2.y,a2.z,a2.w, a3.x,a3.y,a3.z,a3.w};
        float sv[16] = {s0.x,s0.y,s0.z,s0.w, s1.x,s1.y,s1.z,s1.w,
                        s2.x,s2.y,s2.z,s2.w, s3.x,s3.y,s3.z,s3.w};
        #pragma unroll
        for (int k = 0; k < 15; k++) {
            int c = k % 3;
            float d = gv[c] - xt[c];
            float w = exp2f(k2[k] * d * d);
            A[k] = fmaf(mv[k], w, A[k]);
            B[k] = fmaf(sv[k], w, B[k]);
        }
    }
    #pragma unroll
    for (int mask = 8; mask <= 32; mask <<= 1) {
        #pragma unroll
        for (int k = 0; k < 15; k++) {
            A[k] += __shfl_xor(A[k], mask, 64);
            B[k] += __shfl_xor(B[k], mask, 64);
        }
    }
    int lane = tid & 63, wv = tid >> 6;
    if (lane < 8) {
        #pragma unroll
        for (int k = 0; k < 15; k++) { red2[wv][lane][k] = A[k]; red2[wv][lane][15 + k] = B[k]; }
    }
    __syncthreads();
    if (tid < 240) {
        int t2 = tid / 30, v = tid % 30;
        AB[t2][v] = red2[0][t2][v] + red2[1][t2][v] + red2[2][t2][v] + red2[3][t2][v];
    }
    __syncthreads();
    if (tid < 192) {
        int t2 = tid / 24;
        int rem = tid % 24;
        int s = rem / 6, j = rem % 6;
        int tg = tt + t2;
        if (tg < ntar) {
            float val = lob[j];
            const float* ep = eps + ((size_t)s * nb + b) * 15;
            #pragma unroll
            for (int k = 0; k < 15; k++) {
                float h = fmaf(ep[k], AB[t2][15 + k], AB[t2][k]);
                val = fmaf(h, loW[k * 6 + j], val);
            }
            if (j >= 3) val = fmaxf(val, 0.0f) + log1pf(__expf(-fabsf(val)));  // softplus
            out[(((size_t)s * nb + b) * ntar + tg) * 6 + j] = val;
        }
    }
}

// =====================================================================
// Fallback path (generic shapes) — R4 passing versions
// =====================================================================

__global__ __launch_bounds__(1024) void enc_kernel_g(
    const float* __restrict__ x, const float* __restrict__ y,
    const float* __restrict__ xg, const float* __restrict__ enc_sigma,
    const float* __restrict__ gW, const float* __restrict__ gb,
    float* __restrict__ rep_s, int nb, int npts, int M)
{
    __shared__ float sx[6144];
    __shared__ float sy[6144];
    __shared__ float red[16][8][6];
    __shared__ float tot[8][6];
    int b = blockIdx.y;
    int mt = blockIdx.x * 8;
    int tid = threadIdx.x;
    int n3 = npts * 3;
    for (int i = tid; i < n3 && i < 12288; i += 1024) {
        sx[i % 6144] = x[(size_t)b * n3 + i % 6144];
        sy[i % 6144] = y[(size_t)b * n3 + i % 6144];
    }
    int mi = tid & 7, ng = tid >> 3;
    int m = mt + mi;
    bool mv = (m < M);
    float e1[3], g[3];
    for (int c = 0; c < 3; c++) {
        float inv = 1.0f / (__expf(enc_sigma[c]) + EPSF);
        e1[c] = -0.5f * inv * inv;
    }
    for (int c = 0; c < 3; c++) g[c] = mv ? xg[(size_t)(b * M + m) * 3 + c] : 0.0f;
    __syncthreads();
    float h0[3] = {0,0,0}, h1[3] = {0,0,0};
    for (int n = ng; n < npts; n += 128) {
        for (int c = 0; c < 3; c++) {
            float d = sx[n * 3 + c] - g[c];
            float w = __expf(e1[c] * d * d);
            h0[c] += w;
            h1[c] = fmaf(sy[n * 3 + c], w, h1[c]);
        }
    }
    for (int mask = 8; mask <= 32; mask <<= 1) {
        for (int c = 0; c < 3; c++) {
            h0[c] += __shfl_xor(h0[c], mask, 64);
            h1[c] += __shfl_xor(h1[c], mask, 64);
        }
    }
    int lane = tid & 63, wv = tid >> 6;
    if (lane < 8) {
        for (int c = 0; c < 3; c++) { red[wv][lane][c] = h0[c]; red[wv][lane][3 + c] = h1[c]; }
    }
    __syncthreads();
    if (tid < 48) {
        int mi2 = tid & 7, c2 = tid >> 3;
        float s = 0.0f;
        for (int k = 0; k < 16; k++) s += red[k][mi2][c2];
        tot[mi2][c2] = s;
    }
    __syncthreads();
    if (tid < 128) {
        int mi2 = tid & 7, j = tid >> 3;
        int m2 = mt + mi2;
        if (m2 < M) {
            float cat[6];
            for (int c = 0; c < 3; c++) {
                cat[c] = tot[mi2][c];
                cat[3 + c] = tot[mi2][3 + c] / (tot[mi2][c] + EPSF);
            }
            float r = gb[j];
            for (int i = 0; i < 6; i++) r = fmaf(cat[i], gW[i * 16 + j], r);
            rep_s[((size_t)b * 16 + j) * M + m2] = sigmoidf_(r);
        }
    }
}

__global__ __launch_bounds__(256) void rho_kernel_g(
    const float* __restrict__ rep_s,
    const float* __restrict__ w1, const float* __restrict__ b1,
    const float* __restrict__ w2, const float* __restrict__ b2,
    const float* __restrict__ w3, const float* __restrict__ b3,
    const float* __restrict__ linW, const float* __restrict__ linb,
    float* __restrict__ mu, float* __restrict__ stdv,
    int nb, int M)
{
    __shared__ float sWA[5152];
    __shared__ float sWB[5152];
    __shared__ float sIn[16][20];
    __shared__ float sH1[32][16];
    __shared__ float sH2[32][12];
    __shared__ float sH3[32][8];
    int b = blockIdx.y;
    int t0 = blockIdx.x * 8;
    int tid = threadIdx.x;
    {
        const float4* w1v = (const float4*)w1;
        const float4* w2v = (const float4*)w2;
        for (int i4 = tid; i4 < 640; i4 += 256) {
            float4 v = w1v[i4];
            float vv[4] = {v.x, v.y, v.z, v.w};
            for (int j = 0; j < 4; j++) {
                int e = 4 * i4 + j;
                sWA[(e / 80) * 81 + e % 80] = vv[j];
            }
        }
        for (int i4 = tid; i4 < 1280; i4 += 256) {
            float4 v = w2v[i4];
            float vv[4] = {v.x, v.y, v.z, v.w};
            for (int j = 0; j < 4; j++) {
                int e = 4 * i4 + j;
                sWB[(e / 160) * 161 + e % 160] = vv[j];
            }
        }
        for (int idx = tid; idx < 16 * 20; idx += 256) {
            int i = idx / 20, q = idx % 20;
            int mg = t0 - 6 + q;
            sIn[i][q] = (mg >= 0 && mg < M) ? rep_s[((size_t)b * 16 + i) * M + mg] : 0.0f;
        }
    }
    __syncthreads();
    int o = tid >> 3, q0 = tid & 7;
    {
        float a0 = b1[o], a1 = a0;
        for (int i = 0; i < 16; i++) {
            const float* wp = sWA + o * 81 + i * 5;
            float u0 = wp[0], u1 = wp[1], u2 = wp[2], u3 = wp[3], u4 = wp[4];
            const float* ip = &sIn[i][0];
            a0 = fmaf(ip[q0], u0, a0);      a0 = fmaf(ip[q0+1], u1, a0);
            a0 = fmaf(ip[q0+2], u2, a0);    a0 = fmaf(ip[q0+3], u3, a0);
            a0 = fmaf(ip[q0+4], u4, a0);
            a1 = fmaf(ip[q0+8], u0, a1);    a1 = fmaf(ip[q0+9], u1, a1);
            a1 = fmaf(ip[q0+10], u2, a1);   a1 = fmaf(ip[q0+11], u3, a1);
            a1 = fmaf(ip[q0+12], u4, a1);
        }
        int g0 = t0 - 4 + q0, g1 = g0 + 8;
        sH1[o][q0]     = (g0 >= 0 && g0 < M) ? fmaxf(a0, 0.0f) : 0.0f;
        sH1[o][q0 + 8] = (g1 >= 0 && g1 < M) ? fmaxf(a1, 0.0f) : 0.0f;
    }
    __syncthreads();
    float4 wreg[5];
    {
        const float4* w3v = (const float4*)w3;
        for (int h = 0; h < 5; h++) wreg[h] = w3v[tid + 256 * h];
    }
    {
        float a0 = b2[o], a1 = a0;
        bool second = (q0 < 4);
        for (int i = 0; i < 32; i++) {
            const float* wp = sWB + o * 161 + i * 5;
            float u0 = wp[0], u1 = wp[1], u2 = wp[2], u3 = wp[3], u4 = wp[4];
            const float* ip = &sH1[i][0];
            a0 = fmaf(ip[q0], u0, a0);      a0 = fmaf(ip[q0+1], u1, a0);
            a0 = fmaf(ip[q0+2], u2, a0);    a0 = fmaf(ip[q0+3], u3, a0);
            a0 = fmaf(ip[q0+4], u4, a0);
            if (second) {
                a1 = fmaf(ip[q0+8], u0, a1);    a1 = fmaf(ip[q0+9], u1, a1);
                a1 = fmaf(ip[q0+10], u2, a1);   a1 = fmaf(ip[q0+11], u3, a1);
                a1 = fmaf(ip[q0+12], u4, a1);
            }
        }
        int g0 = t0 - 2 + q0, g1 = g0 + 8;
        sH2[o][q0] = (g0 >= 0 && g0 < M) ? fmaxf(a0, 0.0f) : 0.0f;
        if (second) sH2[o][q0 + 8] = (g1 >= 0 && g1 < M) ? fmaxf(a1, 0.0f) : 0.0f;
    }
    for (int h = 0; h < 5; h++) {
        float vv[4] = {wreg[h].x, wreg[h].y, wreg[h].z, wreg[h].w};
        for (int j = 0; j < 4; j++) {
            int e = 4 * (tid + 256 * h) + j;
            sWA[(e / 160) * 161 + e % 160] = vv[j];
        }
    }
    __syncthreads();
    {
        float a0 = b3[o];
        for (int i = 0; i < 32; i++) {
            const float* wp = sWA + o * 161 + i * 5;
            float u0 = wp[0], u1 = wp[1], u2 = wp[2], u3 = wp[3], u4 = wp[4];
            const float* ip = &sH2[i][0];
            a0 = fmaf(ip[q0], u0, a0);      a0 = fmaf(ip[q0+1], u1, a0);
            a0 = fmaf(ip[q0+2], u2, a0);    a0 = fmaf(ip[q0+3], u3, a0);
            a0 = fmaf(ip[q0+4], u4, a0);
        }
        sH3[o][q0] = a0;
    }
    __syncthreads();
    if (tid < 240) {
        int q = tid / 30, j = tid % 30;
        int m = t0 + q;
        if (m < M) {
            float v = linb[j];
            for (int oo = 0; oo < 32; oo++) v = fmaf(sH3[oo][q], linW[oo * 30 + j], v);
            if (j < 15) mu[((size_t)b * M + m) * 16 + j] = v;
            else        stdv[((size_t)b * M + m) * 16 + (j - 15)] = 0.1f + 0.9f * sigmoidf_(v);
        }
    }
}

extern "C" void kernel_launch(void* const* d_in, const int* in_sizes, int n_in,
                              void* d_out, int out_size, void* d_ws, size_t ws_size,
                              hipStream_t stream)
{
    const float* x         = (const float*)d_in[0];
    const float* y         = (const float*)d_in[1];
    const float* x_out     = (const float*)d_in[2];
    const float* x_grid    = (const float*)d_in[3];
    const float* eps_noise = (const float*)d_in[4];
    const float* enc_sigma = (const float*)d_in[5];
    const float* gW        = (const float*)d_in[6];
    const float* gb        = (const float*)d_in[7];
    const float* w1        = (const float*)d_in[8];
    const float* b1        = (const float*)d_in[9];
    const float* w2        = (const float*)d_in[10];
    const float* b2        = (const float*)d_in[11];
    const float* w3        = (const float*)d_in[12];
    const float* b3        = (const float*)d_in[13];
    const float* linW      = (const float*)d_in[14];
    const float* linb      = (const float*)d_in[15];
    const float* int_sigma = (const float*)d_in[16];
    const float* loW       = (const float*)d_in[17];
    const float* lob       = (const float*)d_in[18];
    float* out = (float*)d_out;

    const int NS = 4, C = 3, NBASIS = 5;
    int nb   = in_sizes[4] / (NS * C * NBASIS);       // eps_noise: (NS, nb, 15)
    int npts = in_sizes[0] / (nb * C);
    int ntar = in_sizes[2] / (nb * C);
    int M    = in_sizes[3] / (nb * C);

    float* mu   = (float*)d_ws;                        // (nb, M, 16)
    float* stdv = mu + (size_t)nb * M * 16;            // (nb, M, 16)

    bool fast = (npts == 2048 && M <= 320);
    if (fast) {
        encrho_kernel<<<dim3(16, nb), 512, 0, stream>>>(
            x, y, x_grid, enc_sigma, gW, gb,
            w1, b1, w2, b2, w3, b3, linW, linb, mu, stdv, nb, M);
    } else {
        float* rep_s = stdv + (size_t)nb * M * 16;     // (nb, 16, M)
        enc_kernel_g<<<dim3((M + 7) / 8, nb), 1024, 0, stream>>>(
            x, y, x_grid, enc_sigma, gW, gb, rep_s, nb, npts, M);
        rho_kernel_g<<<dim3((M + 7) / 8, nb), 256, 0, stream>>>(
            rep_s, w1, b1, w2, b2, w3, b3, linW, linb, mu, stdv, nb, M);
    }
    final_kernel<<<dim3((ntar + 7) / 8, nb), 256, 0, stream>>>(
        x_out, x_grid, int_sigma, eps_noise, mu, stdv, loW, lob, out, nb, ntar, M);
}